// Round 1
// baseline (782.915 us; speedup 1.0000x reference)
//
#include <hip/hip_runtime.h>
#include <stdint.h>

#define B_ 8
#define L_ 2500
#define D_ 512
#define Y_ 8921
#define LP 2560   // padded L = 20*128
#define YP 8960   // padded Y = 70*128
#define BLK 128
#define BK 32
#define NKT 16    // 512/32
#define NLT 20    // 2560/128

typedef float f32x4 __attribute__((ext_vector_type(4)));
typedef __bf16 bf16x8 __attribute__((ext_vector_type(8)));
typedef unsigned short u16;
typedef unsigned int u32;

// ---- f32 -> bf16 (RTNE) pack helpers ----
__device__ __forceinline__ u32 pack2(float a, float b) {
  u32 ua = __float_as_uint(a); ua = (ua + 0x7FFFu + ((ua >> 16) & 1u)) >> 16;
  u32 ub = __float_as_uint(b); ub = (ub + 0x7FFFu + ((ub >> 16) & 1u)) >> 16;
  return ua | (ub << 16);
}

// x [B,L,D] f32 -> [B,LP,D] bf16 (pad rows zero)
__global__ void cvt_x_kernel(const float* __restrict__ x, u16* __restrict__ xb) {
  int idx = blockIdx.x * 256 + threadIdx.x;   // one 8-elem chunk
  int row = idx >> 6;                         // b*LP + l
  int c8  = (idx & 63) << 3;
  int b = row / LP;
  int l = row - b * LP;
  uint4 o;
  if (l < L_) {
    const float* s = x + (size_t)(b * L_ + l) * D_ + c8;
    float4 f0 = *(const float4*)s;
    float4 f1 = *(const float4*)(s + 4);
    o.x = pack2(f0.x, f0.y); o.y = pack2(f0.z, f0.w);
    o.z = pack2(f1.x, f1.y); o.w = pack2(f1.z, f1.w);
  } else {
    o = make_uint4(0u, 0u, 0u, 0u);
  }
  *(uint4*)(xb + (size_t)row * D_ + c8) = o;
}

// U,Wf [Y,D] f32 -> [YP,D] bf16 each (pad rows zero)
__global__ void cvt_w_kernel(const float* __restrict__ U, const float* __restrict__ Wf,
                             u16* __restrict__ Ub, u16* __restrict__ Wb) {
  int idx = blockIdx.x * 256 + threadIdx.x;
  const int half = YP * 64;
  const float* src = U; u16* dst = Ub;
  int i = idx;
  if (idx >= half) { i -= half; src = Wf; dst = Wb; }
  int row = i >> 6;
  int c8  = (i & 63) << 3;
  uint4 o;
  if (row < Y_) {
    const float* s = src + (size_t)row * D_ + c8;
    float4 f0 = *(const float4*)s;
    float4 f1 = *(const float4*)(s + 4);
    o.x = pack2(f0.x, f0.y); o.y = pack2(f0.z, f0.w);
    o.z = pack2(f1.x, f1.y); o.w = pack2(f1.z, f1.w);
  } else {
    o = make_uint4(0u, 0u, 0u, 0u);
  }
  *(uint4*)(dst + (size_t)row * D_ + c8) = o;
}

__device__ __forceinline__ void async16(const u16* g, u16* l) {
  __builtin_amdgcn_global_load_lds(
      (const __attribute__((address_space(1))) u32*)g,
      (__attribute__((address_space(3))) u32*)l, 16, 0, 0);
}

// Fused: per (b, y-tile of 128): stream l-tiles of 128, compute att & s via MFMA,
// online softmax, final y + BCE partial.
__global__ __launch_bounds__(256, 2) void fused_kernel(
    const u16* __restrict__ xb,   // [B][LP][D] bf16
    const u16* __restrict__ Ub,   // [YP][D]
    const u16* __restrict__ Wb,   // [YP][D]
    const float* __restrict__ bias,    // [Y]
    const float* __restrict__ target,  // [B][Y]
    float* __restrict__ out)           // [B*Y + 1]
{
  __shared__ __align__(16) u16 sU[BLK * BK];
  __shared__ __align__(16) u16 sW[BLK * BK];
  __shared__ __align__(16) u16 sX[BLK * BK];

  const int t    = threadIdx.x;
  const int lane = t & 63;
  const int wv   = t >> 6;          // wave 0..3, owns y rows [wv*32, wv*32+32)
  const int l16  = lane & 15;
  const int q    = lane >> 4;       // quad 0..3
  const int b    = blockIdx.y;
  const int y0   = blockIdx.x * BLK;

  // staging: thread t loads 16B chunk: row = t>>2 (+64 for round 1), col chunk (t&3)*8
  const int srow = t >> 2;
  const int scol = (t & 3) << 3;
  const u16* gU0 = Ub + (size_t)(y0 + srow) * D_ + scol;
  const u16* gU1 = gU0 + (size_t)64 * D_;
  const u16* gW0 = Wb + (size_t)(y0 + srow) * D_ + scol;
  const u16* gW1 = gW0 + (size_t)64 * D_;
  const u16* gXb = xb + (size_t)b * LP * D_ + (size_t)srow * D_ + scol;
  u16* lU0 = sU + t * 8;  u16* lU1 = sU + 2048 + t * 8;
  u16* lW0 = sW + t * 8;  u16* lW1 = sW + 2048 + t * 8;
  u16* lX0 = sX + t * 8;  u16* lX1 = sX + 2048 + t * 8;

  // running softmax stats per owned y-row (8 rows/lane: ry*4+reg), replicated over 16 lanes
  float M[8], Z[8], W[8];
#pragma unroll
  for (int i = 0; i < 8; ++i) { M[i] = -1e30f; Z[i] = 0.f; W[i] = 0.f; }

  const f32x4 z4 = {0.f, 0.f, 0.f, 0.f};

  for (int lt = 0; lt < NLT; ++lt) {
    const int l0 = lt * BLK;
    const u16* gX0 = gXb + (size_t)l0 * D_;
    const u16* gX1 = gX0 + (size_t)64 * D_;

    f32x4 accA[2][8], accS[2][8];
#pragma unroll
    for (int ry = 0; ry < 2; ++ry)
#pragma unroll
      for (int cl = 0; cl < 8; ++cl) { accA[ry][cl] = z4; accS[ry][cl] = z4; }

    for (int kt = 0; kt < NKT; ++kt) {
      const int ko = kt * BK;
      __syncthreads();                 // previous tile consumed
      async16(gU0 + ko, lU0);
      async16(gU1 + ko, lU1);
      async16(gW0 + ko, lW0);
      async16(gW1 + ko, lW1);
      async16(gX0 + ko, lX0);
      async16(gX1 + ko, lX1);
      __syncthreads();                 // loads visible (compiler inserts vmcnt wait)

      bf16x8 aU0 = *(const bf16x8*)(const void*)(sU + (wv * 32 + l16) * BK + q * 8);
      bf16x8 aU1 = *(const bf16x8*)(const void*)(sU + (wv * 32 + 16 + l16) * BK + q * 8);
      bf16x8 aW0 = *(const bf16x8*)(const void*)(sW + (wv * 32 + l16) * BK + q * 8);
      bf16x8 aW1 = *(const bf16x8*)(const void*)(sW + (wv * 32 + 16 + l16) * BK + q * 8);
#pragma unroll
      for (int cl = 0; cl < 8; ++cl) {
        bf16x8 bX = *(const bf16x8*)(const void*)(sX + (cl * 16 + l16) * BK + q * 8);
        accA[0][cl] = __builtin_amdgcn_mfma_f32_16x16x32_bf16(aU0, bX, accA[0][cl], 0, 0, 0);
        accA[1][cl] = __builtin_amdgcn_mfma_f32_16x16x32_bf16(aU1, bX, accA[1][cl], 0, 0, 0);
        accS[0][cl] = __builtin_amdgcn_mfma_f32_16x16x32_bf16(aW0, bX, accS[0][cl], 0, 0, 0);
        accS[1][cl] = __builtin_amdgcn_mfma_f32_16x16x32_bf16(aW1, bX, accS[1][cl], 0, 0, 0);
      }
    }

    // online softmax update. C/D layout: col(l) = lane&15, row(y) = q*4 + reg
#pragma unroll
    for (int ry = 0; ry < 2; ++ry) {
#pragma unroll
      for (int r = 0; r < 4; ++r) {
        const int si = ry * 4 + r;
        float a[8];
        float tmax = -1e30f;
#pragma unroll
        for (int cl = 0; cl < 8; ++cl) {
          float v = accA[ry][cl][r];
          if (l0 + cl * 16 + l16 >= L_) v = -1e30f;   // mask padded l
          a[cl] = v;
          tmax = fmaxf(tmax, v);
        }
        tmax = fmaxf(tmax, __shfl_xor(tmax, 1));
        tmax = fmaxf(tmax, __shfl_xor(tmax, 2));
        tmax = fmaxf(tmax, __shfl_xor(tmax, 4));
        tmax = fmaxf(tmax, __shfl_xor(tmax, 8));
        const float mnew  = fmaxf(M[si], tmax);
        const float scale = __expf(M[si] - mnew);
        float zl = 0.f, wl = 0.f;
#pragma unroll
        for (int cl = 0; cl < 8; ++cl) {
          float p = __expf(a[cl] - mnew);
          zl += p;
          wl = fmaf(p, accS[ry][cl][r], wl);
        }
        zl += __shfl_xor(zl, 1); zl += __shfl_xor(zl, 2);
        zl += __shfl_xor(zl, 4); zl += __shfl_xor(zl, 8);
        wl += __shfl_xor(wl, 1); wl += __shfl_xor(wl, 2);
        wl += __shfl_xor(wl, 4); wl += __shfl_xor(wl, 8);
        Z[si] = Z[si] * scale + zl;
        W[si] = W[si] * scale + wl;
        M[si] = mnew;
      }
    }
  }

  // epilogue: y = W/Z + bias; BCE partial into loss slot
  float part = 0.f;
#pragma unroll
  for (int ry = 0; ry < 2; ++ry) {
#pragma unroll
    for (int r = 0; r < 4; ++r) {
      const int si = ry * 4 + r;
      const int yg = y0 + wv * 32 + ry * 16 + q * 4 + r;
      if (yg < Y_ && l16 == 0) {
        const float yv = W[si] / Z[si] + bias[yg];
        out[(size_t)b * Y_ + yg] = yv;
        const float tg = target[(size_t)b * Y_ + yg];
        part += fmaxf(yv, 0.f) - yv * tg + log1pf(__expf(-fabsf(yv)));
      }
    }
  }
  part += __shfl_xor(part, 16);
  part += __shfl_xor(part, 32);
  if (lane == 0) atomicAdd(out + (size_t)B_ * Y_, part * (1.0f / (B_ * Y_)));
}

extern "C" void kernel_launch(void* const* d_in, const int* in_sizes, int n_in,
                              void* d_out, int out_size, void* d_ws, size_t ws_size,
                              hipStream_t stream) {
  const float* x      = (const float*)d_in[0];
  const float* target = (const float*)d_in[1];
  // d_in[2] = text_inputs (unused by reference)
  const float* U      = (const float*)d_in[3];
  const float* Wf     = (const float*)d_in[4];
  const float* bias   = (const float*)d_in[5];
  float* out = (float*)d_out;

  u16* xb = (u16*)d_ws;                      // [B][LP][D]   20.97 MB
  u16* Ub = xb + (size_t)B_ * LP * D_;       // [YP][D]       9.18 MB
  u16* Wb = Ub + (size_t)YP * D_;            // [YP][D]       9.18 MB

  hipMemsetAsync(out + (size_t)B_ * Y_, 0, sizeof(float), stream);
  cvt_x_kernel<<<dim3((B_ * LP * 64) / 256), 256, 0, stream>>>(x, xb);
  cvt_w_kernel<<<dim3((2 * YP * 64) / 256), 256, 0, stream>>>(U, Wf, Ub, Wb);
  fused_kernel<<<dim3(YP / BLK, B_), 256, 0, stream>>>(xb, Ub, Wb, bias, target, out);
}

// Round 2
// 596.475 us; speedup vs baseline: 1.3126x; 1.3126x over previous
//
#include <hip/hip_runtime.h>
#include <stdint.h>

#define B_ 8
#define L_ 2500
#define D_ 512
#define Y_ 8921
#define LP 2560   // padded L = 20*128
#define YP 8960   // padded Y = 70*128
#define BLK 128
#define BK 32
#define NKT 16    // 512/32
#define NS 4      // l-splits (blocks along L)
#define LTS 5     // l-tiles of 128 per split (20/NS)

typedef float f32x4 __attribute__((ext_vector_type(4)));
typedef __bf16 bf16x8 __attribute__((ext_vector_type(8)));
typedef unsigned short u16;
typedef unsigned int u32;

// ---- f32 -> bf16 (RTNE) pack helpers ----
__device__ __forceinline__ u32 pack2(float a, float b) {
  u32 ua = __float_as_uint(a); ua = (ua + 0x7FFFu + ((ua >> 16) & 1u)) >> 16;
  u32 ub = __float_as_uint(b); ub = (ub + 0x7FFFu + ((ub >> 16) & 1u)) >> 16;
  return ua | (ub << 16);
}

// x [B,L,D] f32 -> [B,LP,D] bf16 (pad rows zero)
__global__ void cvt_x_kernel(const float* __restrict__ x, u16* __restrict__ xb) {
  int idx = blockIdx.x * 256 + threadIdx.x;   // one 8-elem chunk
  int row = idx >> 6;                         // b*LP + l
  int c8  = (idx & 63) << 3;
  int b = row / LP;
  int l = row - b * LP;
  uint4 o;
  if (l < L_) {
    const float* s = x + (size_t)(b * L_ + l) * D_ + c8;
    float4 f0 = *(const float4*)s;
    float4 f1 = *(const float4*)(s + 4);
    o.x = pack2(f0.x, f0.y); o.y = pack2(f0.z, f0.w);
    o.z = pack2(f1.x, f1.y); o.w = pack2(f1.z, f1.w);
  } else {
    o = make_uint4(0u, 0u, 0u, 0u);
  }
  *(uint4*)(xb + (size_t)row * D_ + c8) = o;
}

// U,Wf [Y,D] f32 -> [YP,D] bf16 each (pad rows zero)
__global__ void cvt_w_kernel(const float* __restrict__ U, const float* __restrict__ Wf,
                             u16* __restrict__ Ub, u16* __restrict__ Wb) {
  int idx = blockIdx.x * 256 + threadIdx.x;
  const int half = YP * 64;
  const float* src = U; u16* dst = Ub;
  int i = idx;
  if (idx >= half) { i -= half; src = Wf; dst = Wb; }
  int row = i >> 6;
  int c8  = (i & 63) << 3;
  uint4 o;
  if (row < Y_) {
    const float* s = src + (size_t)row * D_ + c8;
    float4 f0 = *(const float4*)s;
    float4 f1 = *(const float4*)(s + 4);
    o.x = pack2(f0.x, f0.y); o.y = pack2(f0.z, f0.w);
    o.z = pack2(f1.x, f1.y); o.w = pack2(f1.z, f1.w);
  } else {
    o = make_uint4(0u, 0u, 0u, 0u);
  }
  *(uint4*)(dst + (size_t)row * D_ + c8) = o;
}

__device__ __forceinline__ void async16(const u16* g, u16* l) {
  __builtin_amdgcn_global_load_lds(
      (const __attribute__((address_space(1))) u32*)g,
      (__attribute__((address_space(3))) u32*)l, 16, 0, 0);
}

// Fused per (y-tile 128, b, l-split): stream LTS l-tiles of 128, MFMA att & s,
// online softmax; write partial (M,Z,W) per y-row to ws.
// Partial layout: part[((b*70 + yt)*NS + s)*384 + {0,128,256} + ylocal]
__global__ __launch_bounds__(256, 2) void fused_kernel(
    const u16* __restrict__ xb,   // [B][LP][D] bf16
    const u16* __restrict__ Ub,   // [YP][D]
    const u16* __restrict__ Wb,   // [YP][D]
    float* __restrict__ part)
{
  __shared__ __align__(16) u16 sU[BLK * BK];
  __shared__ __align__(16) u16 sW[BLK * BK];
  __shared__ __align__(16) u16 sX[BLK * BK];

  const int t    = threadIdx.x;
  const int lane = t & 63;
  const int wv   = t >> 6;          // wave 0..3, owns y rows [wv*32, wv*32+32)
  const int l16  = lane & 15;
  const int q    = lane >> 4;       // quad 0..3
  const int b    = blockIdx.y;
  const int y0   = blockIdx.x * BLK;
  const int s    = blockIdx.z;      // l-split

  // staging: thread t loads 16B chunk: row = t>>2 (+64 for round 1), col chunk (t&3)*8
  const int srow = t >> 2;
  const int scol = (t & 3) << 3;
  const u16* gU0 = Ub + (size_t)(y0 + srow) * D_ + scol;
  const u16* gU1 = gU0 + (size_t)64 * D_;
  const u16* gW0 = Wb + (size_t)(y0 + srow) * D_ + scol;
  const u16* gW1 = gW0 + (size_t)64 * D_;
  const u16* gXb = xb + (size_t)b * LP * D_ + (size_t)srow * D_ + scol;
  u16* lU0 = sU + t * 8;  u16* lU1 = sU + 2048 + t * 8;
  u16* lW0 = sW + t * 8;  u16* lW1 = sW + 2048 + t * 8;
  u16* lX0 = sX + t * 8;  u16* lX1 = sX + 2048 + t * 8;

  // running softmax stats per owned y-row (8 rows/lane: ry*4+reg), replicated over 16 lanes
  float M[8], Z[8], W[8];
#pragma unroll
  for (int i = 0; i < 8; ++i) { M[i] = -1e30f; Z[i] = 0.f; W[i] = 0.f; }

  const f32x4 z4 = {0.f, 0.f, 0.f, 0.f};

  for (int ltl = 0; ltl < LTS; ++ltl) {
    const int l0 = (s * LTS + ltl) * BLK;
    const u16* gX0 = gXb + (size_t)l0 * D_;
    const u16* gX1 = gX0 + (size_t)64 * D_;

    f32x4 accA[2][8], accS[2][8];
#pragma unroll
    for (int ry = 0; ry < 2; ++ry)
#pragma unroll
      for (int cl = 0; cl < 8; ++cl) { accA[ry][cl] = z4; accS[ry][cl] = z4; }

    for (int kt = 0; kt < NKT; ++kt) {
      const int ko = kt * BK;
      __syncthreads();                 // previous tile consumed
      async16(gU0 + ko, lU0);
      async16(gU1 + ko, lU1);
      async16(gW0 + ko, lW0);
      async16(gW1 + ko, lW1);
      async16(gX0 + ko, lX0);
      async16(gX1 + ko, lX1);
      __syncthreads();                 // loads visible (compiler inserts vmcnt wait)

      bf16x8 aU0 = *(const bf16x8*)(const void*)(sU + (wv * 32 + l16) * BK + q * 8);
      bf16x8 aU1 = *(const bf16x8*)(const void*)(sU + (wv * 32 + 16 + l16) * BK + q * 8);
      bf16x8 aW0 = *(const bf16x8*)(const void*)(sW + (wv * 32 + l16) * BK + q * 8);
      bf16x8 aW1 = *(const bf16x8*)(const void*)(sW + (wv * 32 + 16 + l16) * BK + q * 8);
#pragma unroll
      for (int cl = 0; cl < 8; ++cl) {
        bf16x8 bX = *(const bf16x8*)(const void*)(sX + (cl * 16 + l16) * BK + q * 8);
        accA[0][cl] = __builtin_amdgcn_mfma_f32_16x16x32_bf16(aU0, bX, accA[0][cl], 0, 0, 0);
        accA[1][cl] = __builtin_amdgcn_mfma_f32_16x16x32_bf16(aU1, bX, accA[1][cl], 0, 0, 0);
        accS[0][cl] = __builtin_amdgcn_mfma_f32_16x16x32_bf16(aW0, bX, accS[0][cl], 0, 0, 0);
        accS[1][cl] = __builtin_amdgcn_mfma_f32_16x16x32_bf16(aW1, bX, accS[1][cl], 0, 0, 0);
      }
    }

    // online softmax update. C/D layout: col(l) = lane&15, row(y) = q*4 + reg
#pragma unroll
    for (int ry = 0; ry < 2; ++ry) {
#pragma unroll
      for (int r = 0; r < 4; ++r) {
        const int si = ry * 4 + r;
        float a[8];
        float tmax = -1e30f;
#pragma unroll
        for (int cl = 0; cl < 8; ++cl) {
          float v = accA[ry][cl][r];
          if (l0 + cl * 16 + l16 >= L_) v = -1e30f;   // mask padded l
          a[cl] = v;
          tmax = fmaxf(tmax, v);
        }
        tmax = fmaxf(tmax, __shfl_xor(tmax, 1));
        tmax = fmaxf(tmax, __shfl_xor(tmax, 2));
        tmax = fmaxf(tmax, __shfl_xor(tmax, 4));
        tmax = fmaxf(tmax, __shfl_xor(tmax, 8));
        const float mnew  = fmaxf(M[si], tmax);
        const float scale = __expf(M[si] - mnew);
        float zl = 0.f, wl = 0.f;
#pragma unroll
        for (int cl = 0; cl < 8; ++cl) {
          float p = __expf(a[cl] - mnew);
          zl += p;
          wl = fmaf(p, accS[ry][cl][r], wl);
        }
        zl += __shfl_xor(zl, 1); zl += __shfl_xor(zl, 2);
        zl += __shfl_xor(zl, 4); zl += __shfl_xor(zl, 8);
        wl += __shfl_xor(wl, 1); wl += __shfl_xor(wl, 2);
        wl += __shfl_xor(wl, 4); wl += __shfl_xor(wl, 8);
        Z[si] = Z[si] * scale + zl;
        W[si] = W[si] * scale + wl;
        M[si] = mnew;
      }
    }
  }

  // write partial (M,Z,W) per owned y-row; replicated over l16 lanes -> only l16==0 writes
  if (l16 == 0) {
    float* p = part + ((size_t)(b * 70 + blockIdx.x) * NS + s) * 384;
#pragma unroll
    for (int ry = 0; ry < 2; ++ry) {
#pragma unroll
      for (int r = 0; r < 4; ++r) {
        const int si = ry * 4 + r;
        const int yl = wv * 32 + ry * 16 + q * 4 + r;
        p[yl]       = M[si];
        p[128 + yl] = Z[si];
        p[256 + yl] = W[si];
      }
    }
  }
}

// Merge NS partials per (b,y); y = W/Z + bias; BCE partial -> atomicAdd.
__global__ void combine_kernel(const float* __restrict__ part,
                               const float* __restrict__ bias,
                               const float* __restrict__ target,
                               float* __restrict__ out) {
  const int idx = blockIdx.x * 256 + threadIdx.x;
  float lpart = 0.f;
  if (idx < B_ * Y_) {
    const int b = idx / Y_;
    const int y = idx - b * Y_;
    const int yt = y >> 7, yl = y & 127;
    const float* p = part + ((size_t)(b * 70 + yt) * NS) * 384 + yl;
    float M = -1e30f;
#pragma unroll
    for (int s2 = 0; s2 < NS; ++s2) M = fmaxf(M, p[s2 * 384]);
    float Z = 0.f, W = 0.f;
#pragma unroll
    for (int s2 = 0; s2 < NS; ++s2) {
      const float e = __expf(p[s2 * 384] - M);
      Z = fmaf(p[s2 * 384 + 128], e, Z);
      W = fmaf(p[s2 * 384 + 256], e, W);
    }
    const float yv = W / Z + bias[y];
    out[idx] = yv;
    const float tg = target[idx];
    lpart = fmaxf(yv, 0.f) - yv * tg + log1pf(__expf(-fabsf(yv)));
  }
  lpart += __shfl_xor(lpart, 1);  lpart += __shfl_xor(lpart, 2);
  lpart += __shfl_xor(lpart, 4);  lpart += __shfl_xor(lpart, 8);
  lpart += __shfl_xor(lpart, 16); lpart += __shfl_xor(lpart, 32);
  if ((threadIdx.x & 63) == 0)
    atomicAdd(out + (size_t)B_ * Y_, lpart * (1.0f / (B_ * Y_)));
}

extern "C" void kernel_launch(void* const* d_in, const int* in_sizes, int n_in,
                              void* d_out, int out_size, void* d_ws, size_t ws_size,
                              hipStream_t stream) {
  const float* x      = (const float*)d_in[0];
  const float* target = (const float*)d_in[1];
  // d_in[2] = text_inputs (unused by reference)
  const float* U      = (const float*)d_in[3];
  const float* Wf     = (const float*)d_in[4];
  const float* bias   = (const float*)d_in[5];
  float* out = (float*)d_out;

  u16* xb = (u16*)d_ws;                      // [B][LP][D]   20.97 MB
  u16* Ub = xb + (size_t)B_ * LP * D_;       // [YP][D]       9.18 MB
  u16* Wb = Ub + (size_t)YP * D_;            // [YP][D]       9.18 MB
  float* part = (float*)(Wb + (size_t)YP * D_);  // [B][70][NS][384] f32  3.44 MB

  hipMemsetAsync(out + (size_t)B_ * Y_, 0, sizeof(float), stream);
  cvt_x_kernel<<<dim3((B_ * LP * 64) / 256), 256, 0, stream>>>(x, xb);
  cvt_w_kernel<<<dim3((2 * YP * 64) / 256), 256, 0, stream>>>(U, Wf, Ub, Wb);
  fused_kernel<<<dim3(YP / BLK, B_, NS), 256, 0, stream>>>(xb, Ub, Wb, part);
  combine_kernel<<<dim3((B_ * Y_ + 255) / 256), 256, 0, stream>>>(part, bias, target, out);
}

// Round 3
// 568.751 us; speedup vs baseline: 1.3766x; 1.0487x over previous
//
#include <hip/hip_runtime.h>
#include <stdint.h>

#define B_ 8
#define L_ 2500
#define D_ 512
#define Y_ 8921
#define LP 2560   // padded L = 20*128
#define YP 8960   // padded Y = 70*128
#define BLK 128
#define BK 32
#define NKT 16    // 512/32
#define NS 4      // l-splits (blocks along L)
#define LTS 5     // l-tiles of 128 per split (20/NS)

typedef float f32x4 __attribute__((ext_vector_type(4)));
typedef __bf16 bf16x8 __attribute__((ext_vector_type(8)));
typedef unsigned short u16;
typedef unsigned int u32;

// ---- f32 -> bf16 (RTNE) pack helpers ----
__device__ __forceinline__ u32 pack2(float a, float b) {
  u32 ua = __float_as_uint(a); ua = (ua + 0x7FFFu + ((ua >> 16) & 1u)) >> 16;
  u32 ub = __float_as_uint(b); ub = (ub + 0x7FFFu + ((ub >> 16) & 1u)) >> 16;
  return ua | (ub << 16);
}

// x [B,L,D] f32 -> [B,LP,D] bf16 (pad rows zero)
__global__ void cvt_x_kernel(const float* __restrict__ x, u16* __restrict__ xb) {
  int idx = blockIdx.x * 256 + threadIdx.x;   // one 8-elem chunk
  int row = idx >> 6;                         // b*LP + l
  int c8  = (idx & 63) << 3;
  int b = row / LP;
  int l = row - b * LP;
  uint4 o;
  if (l < L_) {
    const float* s = x + (size_t)(b * L_ + l) * D_ + c8;
    float4 f0 = *(const float4*)s;
    float4 f1 = *(const float4*)(s + 4);
    o.x = pack2(f0.x, f0.y); o.y = pack2(f0.z, f0.w);
    o.z = pack2(f1.x, f1.y); o.w = pack2(f1.z, f1.w);
  } else {
    o = make_uint4(0u, 0u, 0u, 0u);
  }
  *(uint4*)(xb + (size_t)row * D_ + c8) = o;
}

// U,Wf [Y,D] f32 -> [YP,D] bf16 each (pad rows zero)
__global__ void cvt_w_kernel(const float* __restrict__ U, const float* __restrict__ Wf,
                             u16* __restrict__ Ub, u16* __restrict__ Wb) {
  int idx = blockIdx.x * 256 + threadIdx.x;
  const int half = YP * 64;
  const float* src = U; u16* dst = Ub;
  int i = idx;
  if (idx >= half) { i -= half; src = Wf; dst = Wb; }
  int row = i >> 6;
  int c8  = (i & 63) << 3;
  uint4 o;
  if (row < Y_) {
    const float* s = src + (size_t)row * D_ + c8;
    float4 f0 = *(const float4*)s;
    float4 f1 = *(const float4*)(s + 4);
    o.x = pack2(f0.x, f0.y); o.y = pack2(f0.z, f0.w);
    o.z = pack2(f1.x, f1.y); o.w = pack2(f1.z, f1.w);
  } else {
    o = make_uint4(0u, 0u, 0u, 0u);
  }
  *(uint4*)(dst + (size_t)row * D_ + c8) = o;
}

__device__ __forceinline__ void async16(const u16* g, u16* l) {
  __builtin_amdgcn_global_load_lds(
      (const __attribute__((address_space(1))) u32*)g,
      (__attribute__((address_space(3))) u32*)l, 16, 0, 0);
}

// Fused per (y-tile 128, b, l-split): stream LTS l-tiles of 128, MFMA att & s,
// PER-LANE online softmax (cross-lane merge deferred to kernel end).
// Partial layout: part[((b*70 + yt)*NS + s)*384 + {0,128,256} + ylocal]
__global__ __launch_bounds__(256, 2) void fused_kernel(
    const u16* __restrict__ xb,   // [B][LP][D] bf16
    const u16* __restrict__ Ub,   // [YP][D]
    const u16* __restrict__ Wb,   // [YP][D]
    float* __restrict__ part)
{
  __shared__ __align__(16) u16 sU[BLK * BK];
  __shared__ __align__(16) u16 sW[BLK * BK];
  __shared__ __align__(16) u16 sX[BLK * BK];

  const int t    = threadIdx.x;
  const int lane = t & 63;
  const int wv   = t >> 6;          // wave 0..3, owns y rows [wv*32, wv*32+32)
  const int l16  = lane & 15;
  const int q    = lane >> 4;       // quad 0..3
  const int b    = blockIdx.y;
  const int y0   = blockIdx.x * BLK;
  const int s    = blockIdx.z;      // l-split

  // staging: thread t loads 16B chunk: row = t>>2 (+64 for round 1), col chunk (t&3)*8
  const int srow = t >> 2;
  const int scol = (t & 3) << 3;
  const u16* gU0 = Ub + (size_t)(y0 + srow) * D_ + scol;
  const u16* gU1 = gU0 + (size_t)64 * D_;
  const u16* gW0 = Wb + (size_t)(y0 + srow) * D_ + scol;
  const u16* gW1 = gW0 + (size_t)64 * D_;
  const u16* gXb = xb + (size_t)b * LP * D_ + (size_t)srow * D_ + scol;
  u16* lU0 = sU + t * 8;  u16* lU1 = sU + 2048 + t * 8;
  u16* lW0 = sW + t * 8;  u16* lW1 = sW + 2048 + t * 8;
  u16* lX0 = sX + t * 8;  u16* lX1 = sX + 2048 + t * 8;

  // PER-LANE running softmax stats: each lane covers its 8 columns (cl*16+l16)
  // for each of its 8 y-rows (si = ry*4+r).
  float M[8], Z[8], W[8];
#pragma unroll
  for (int i = 0; i < 8; ++i) { M[i] = -1e30f; Z[i] = 0.f; W[i] = 0.f; }

  const f32x4 z4 = {0.f, 0.f, 0.f, 0.f};

  for (int ltl = 0; ltl < LTS; ++ltl) {
    const int l0 = (s * LTS + ltl) * BLK;
    const u16* gX0 = gXb + (size_t)l0 * D_;
    const u16* gX1 = gX0 + (size_t)64 * D_;

    f32x4 accA[2][8], accS[2][8];
#pragma unroll
    for (int ry = 0; ry < 2; ++ry)
#pragma unroll
      for (int cl = 0; cl < 8; ++cl) { accA[ry][cl] = z4; accS[ry][cl] = z4; }

    for (int kt = 0; kt < NKT; ++kt) {
      const int ko = kt * BK;
      __syncthreads();                 // previous tile consumed
      async16(gU0 + ko, lU0);
      async16(gU1 + ko, lU1);
      async16(gW0 + ko, lW0);
      async16(gW1 + ko, lW1);
      async16(gX0 + ko, lX0);
      async16(gX1 + ko, lX1);
      __syncthreads();                 // loads visible (compiler inserts vmcnt wait)

      bf16x8 aU0 = *(const bf16x8*)(const void*)(sU + (wv * 32 + l16) * BK + q * 8);
      bf16x8 aU1 = *(const bf16x8*)(const void*)(sU + (wv * 32 + 16 + l16) * BK + q * 8);
      bf16x8 aW0 = *(const bf16x8*)(const void*)(sW + (wv * 32 + l16) * BK + q * 8);
      bf16x8 aW1 = *(const bf16x8*)(const void*)(sW + (wv * 32 + 16 + l16) * BK + q * 8);
#pragma unroll
      for (int cl = 0; cl < 8; ++cl) {
        bf16x8 bX = *(const bf16x8*)(const void*)(sX + (cl * 16 + l16) * BK + q * 8);
        accA[0][cl] = __builtin_amdgcn_mfma_f32_16x16x32_bf16(aU0, bX, accA[0][cl], 0, 0, 0);
        accA[1][cl] = __builtin_amdgcn_mfma_f32_16x16x32_bf16(aU1, bX, accA[1][cl], 0, 0, 0);
        accS[0][cl] = __builtin_amdgcn_mfma_f32_16x16x32_bf16(aW0, bX, accS[0][cl], 0, 0, 0);
        accS[1][cl] = __builtin_amdgcn_mfma_f32_16x16x32_bf16(aW1, bX, accS[1][cl], 0, 0, 0);
      }
    }

    // per-lane online softmax update (no shuffles). C/D: col(l)=lane&15, row(y)=q*4+reg
    const bool boundary = (l0 + BLK > L_);   // wave-uniform; true for 1 of 20 tiles
#pragma unroll
    for (int ry = 0; ry < 2; ++ry) {
#pragma unroll
      for (int r = 0; r < 4; ++r) {
        const int si = ry * 4 + r;
        float a[8];
        if (boundary) {
#pragma unroll
          for (int cl = 0; cl < 8; ++cl) {
            float v = accA[ry][cl][r];
            a[cl] = (l0 + cl * 16 + l16 >= L_) ? -1e30f : v;
          }
        } else {
#pragma unroll
          for (int cl = 0; cl < 8; ++cl) a[cl] = accA[ry][cl][r];
        }
        float tmax = a[0];
#pragma unroll
        for (int cl = 1; cl < 8; ++cl) tmax = fmaxf(tmax, a[cl]);
        const float mnew  = fmaxf(M[si], tmax);
        const float scale = __expf(M[si] - mnew);
        float zl = 0.f, wl = 0.f;
#pragma unroll
        for (int cl = 0; cl < 8; ++cl) {
          float p = __expf(a[cl] - mnew);
          zl += p;
          wl = fmaf(p, accS[ry][cl][r], wl);
        }
        Z[si] = fmaf(Z[si], scale, zl);
        W[si] = fmaf(W[si], scale, wl);
        M[si] = mnew;
      }
    }
  }

  // ONE cross-lane merge over the l16 group (butterfly with exp rescale)
#pragma unroll
  for (int si = 0; si < 8; ++si) {
    float M0 = M[si], Z0 = Z[si], W0 = W[si];
#pragma unroll
    for (int st = 1; st <= 8; st <<= 1) {
      const float Mo = __shfl_xor(M0, st);
      const float Zo = __shfl_xor(Z0, st);
      const float Wo = __shfl_xor(W0, st);
      const float mn = fmaxf(M0, Mo);
      const float sa = __expf(M0 - mn);
      const float sb = __expf(Mo - mn);
      Z0 = Z0 * sa + Zo * sb;
      W0 = W0 * sa + Wo * sb;
      M0 = mn;
    }
    M[si] = M0; Z[si] = Z0; W[si] = W0;
  }

  // write partial (M,Z,W) per owned y-row; stats now replicated -> l16==0 writes
  if (l16 == 0) {
    float* p = part + ((size_t)(b * 70 + blockIdx.x) * NS + s) * 384;
#pragma unroll
    for (int ry = 0; ry < 2; ++ry) {
#pragma unroll
      for (int r = 0; r < 4; ++r) {
        const int si = ry * 4 + r;
        const int yl = wv * 32 + ry * 16 + q * 4 + r;
        p[yl]       = M[si];
        p[128 + yl] = Z[si];
        p[256 + yl] = W[si];
      }
    }
  }
}

// Merge NS partials per (b,y); y = W/Z + bias; BCE partial -> atomicAdd.
__global__ void combine_kernel(const float* __restrict__ part,
                               const float* __restrict__ bias,
                               const float* __restrict__ target,
                               float* __restrict__ out) {
  const int idx = blockIdx.x * 256 + threadIdx.x;
  float lpart = 0.f;
  if (idx < B_ * Y_) {
    const int b = idx / Y_;
    const int y = idx - b * Y_;
    const int yt = y >> 7, yl = y & 127;
    const float* p = part + ((size_t)(b * 70 + yt) * NS) * 384 + yl;
    float M = -1e30f;
#pragma unroll
    for (int s2 = 0; s2 < NS; ++s2) M = fmaxf(M, p[s2 * 384]);
    float Z = 0.f, W = 0.f;
#pragma unroll
    for (int s2 = 0; s2 < NS; ++s2) {
      const float e = __expf(p[s2 * 384] - M);
      Z = fmaf(p[s2 * 384 + 128], e, Z);
      W = fmaf(p[s2 * 384 + 256], e, W);
    }
    const float yv = W / Z + bias[y];
    out[idx] = yv;
    const float tg = target[idx];
    lpart = fmaxf(yv, 0.f) - yv * tg + log1pf(__expf(-fabsf(yv)));
  }
  lpart += __shfl_xor(lpart, 1);  lpart += __shfl_xor(lpart, 2);
  lpart += __shfl_xor(lpart, 4);  lpart += __shfl_xor(lpart, 8);
  lpart += __shfl_xor(lpart, 16); lpart += __shfl_xor(lpart, 32);
  if ((threadIdx.x & 63) == 0)
    atomicAdd(out + (size_t)B_ * Y_, lpart * (1.0f / (B_ * Y_)));
}

extern "C" void kernel_launch(void* const* d_in, const int* in_sizes, int n_in,
                              void* d_out, int out_size, void* d_ws, size_t ws_size,
                              hipStream_t stream) {
  const float* x      = (const float*)d_in[0];
  const float* target = (const float*)d_in[1];
  // d_in[2] = text_inputs (unused by reference)
  const float* U      = (const float*)d_in[3];
  const float* Wf     = (const float*)d_in[4];
  const float* bias   = (const float*)d_in[5];
  float* out = (float*)d_out;

  u16* xb = (u16*)d_ws;                      // [B][LP][D]   20.97 MB
  u16* Ub = xb + (size_t)B_ * LP * D_;       // [YP][D]       9.18 MB
  u16* Wb = Ub + (size_t)YP * D_;            // [YP][D]       9.18 MB
  float* part = (float*)(Wb + (size_t)YP * D_);  // [B][70][NS][384] f32  3.44 MB

  hipMemsetAsync(out + (size_t)B_ * Y_, 0, sizeof(float), stream);
  cvt_x_kernel<<<dim3((B_ * LP * 64) / 256), 256, 0, stream>>>(x, xb);
  cvt_w_kernel<<<dim3((2 * YP * 64) / 256), 256, 0, stream>>>(U, Wf, Ub, Wb);
  fused_kernel<<<dim3(YP / BLK, B_, NS), 256, 0, stream>>>(xb, Ub, Wb, part);
  combine_kernel<<<dim3((B_ * Y_ + 255) / 256), 256, 0, stream>>>(part, bias, target, out);
}